// Round 5
// baseline (692.233 us; speedup 1.0000x reference)
//
#include <hip/hip_runtime.h>

// ---------------------------------------------------------------------------
// Fully-fused WaveNet forward (MFMA). Key facts:
//  * All dilated convs are K=2, dil=2 (reference bug) -> receptive field = 25.
//  * One block = (batch b, 128-col time chunk) with 32-col left halo (160 cols).
//    Left-edge erosion (2 cols/layer) never reaches central 128 cols.
//  * Inputs f32 + int32 tokens (confirmed R4); OUTPUT IS F32 (R2-R4 bug: the
//    reference returns float32, so d_out is float* -- bf16 writes into an f32
//    buffer produced the observed 7.14e-3 decorrelated-half-zero signature).
//  * Interior bf16, f32 MFMA accumulation, mfma_f32_16x16x32_bf16 everywhere.
//  * Weights pre-swizzled+converted to bf16 A-fragment order in d_ws by prep.
//  * Skip accumulator [256 x 128] f32 held in AGPRs across all 12 layers.
// ---------------------------------------------------------------------------

typedef __attribute__((ext_vector_type(8))) short short8;   // 8 bf16 (A/B frag)
typedef __attribute__((ext_vector_type(4))) short short4v;  // 4 bf16 pack
typedef __attribute__((ext_vector_type(4))) float f32x4;    // accumulator

#define T_TOK 8192
#define TT    128     // central cols per block
#define HALO  32
#define XSTE  136     // x LDS col stride (128 ch + 8 pad), 272B = 17*16B
#define GSTE  72      // g LDS col stride (64 ch + 8 pad), 144B = 9*16B
#define SSTE  264     // s/t1 LDS col stride (256 ch + 8 pad), 528B = 33*16B
#define X_OFF 0
#define G_OFF 43520                  // 160*136*2
#define S_OFF 66560                  // + 160*72*2
#define LDS_BYTES 134144             // + 128*264*2

// fragment-section bases in d_ws (bf16 elems)
#define FI  0          // init conv: 2 taps * 8 mt * 8 kc * 512
#define FD  65536      // dil conv: 12 * 2 * 8 * 4 * 512
#define FS  458752     // skip:     12 * 16 * 2 * 512   (scaled by 1/12)
#define FR  655360     // res:      12 * 8 * 2 * 512
#define FO1 753664     // out1:     16 * 8 * 512
#define FO2 819200     // out2:     16 * 8 * 512
#define FRAG_TOTAL 884736
#define BSK_BYTE_OFF  (FRAG_TOTAL * 2)          // 256 floats
#define EMBF_BYTE_OFF (BSK_BYTE_OFF + 1024)     // 65536 bf16
#define PREP_TOTAL (FRAG_TOTAL + 256 + 65536)   // = 950528 = 3713*256

#define MFMA(a, b, c) __builtin_amdgcn_mfma_f32_16x16x32_bf16(a, b, c, 0, 0, 0)

__device__ __forceinline__ unsigned short f2b(float f) {
  unsigned int x = __builtin_bit_cast(unsigned int, f);
  return (unsigned short)((x + 0x7fffu + ((x >> 16) & 1u)) >> 16);  // RNE
}

// ---------------- prep: swizzle weights into A-fragment order ----------------
// frag element (outer, lane, j): value = W[mt*16 + (lane&15)][kc*32 + (lane>>4)*8 + j]
__global__ void __launch_bounds__(256) prep_kernel(
    const float* __restrict__ emb,
    const float* __restrict__ w_init,
    const float* __restrict__ w_dil,
    const float* __restrict__ w_skip,
    const float* __restrict__ w_res,
    const float* __restrict__ w_out1,
    const float* __restrict__ w_out2,
    const float* __restrict__ b_skip,
    unsigned short* __restrict__ frags,
    float* __restrict__ bsk,
    unsigned short* __restrict__ embf)
{
  int flat = blockIdx.x * 256 + threadIdx.x;
  if (flat < FRAG_TOTAL) {
    float val;
    if (flat < FD) {                       // init conv  W[128][256][2]
      int rel = flat;
      int j = rel & 7, lane = (rel >> 3) & 63, outer = rel >> 9;
      int kc = outer & 7, mt = (outer >> 3) & 7, tap = outer >> 6;
      int m = mt * 16 + (lane & 15);
      int k = kc * 32 + (lane >> 4) * 8 + j;
      val = w_init[(m * 256 + k) * 2 + tap];
    } else if (flat < FS) {                // dil conv  W[12][128][128][2]
      int rel = flat - FD;
      int j = rel & 7, lane = (rel >> 3) & 63, outer = rel >> 9;
      int kc = outer & 3, mt = (outer >> 2) & 7, tap = (outer >> 5) & 1, l = outer >> 6;
      int m = mt * 16 + (lane & 15);
      int k = kc * 32 + (lane >> 4) * 8 + j;
      val = w_dil[((l * 128 + m) * 128 + k) * 2 + tap];
    } else if (flat < FR) {                // skip  W[12][256][64], scaled 1/12
      int rel = flat - FS;
      int j = rel & 7, lane = (rel >> 3) & 63, outer = rel >> 9;
      int kc = outer & 1, mt = (outer >> 1) & 15, l = outer >> 5;
      int m = mt * 16 + (lane & 15);
      int k = kc * 32 + (lane >> 4) * 8 + j;
      val = w_skip[(l * 256 + m) * 64 + k] * (1.0f / 12.0f);
    } else if (flat < FO1) {               // res  W[12][128][64]
      int rel = flat - FR;
      int j = rel & 7, lane = (rel >> 3) & 63, outer = rel >> 9;
      int kc = outer & 1, mt = (outer >> 1) & 7, l = outer >> 4;
      int m = mt * 16 + (lane & 15);
      int k = kc * 32 + (lane >> 4) * 8 + j;
      val = w_res[(l * 128 + m) * 64 + k];
    } else if (flat < FO2) {               // out1  W[256][256]
      int rel = flat - FO1;
      int j = rel & 7, lane = (rel >> 3) & 63, outer = rel >> 9;
      int kc = outer & 7, mt = outer >> 3;
      int m = mt * 16 + (lane & 15);
      int k = kc * 32 + (lane >> 4) * 8 + j;
      val = w_out1[m * 256 + k];
    } else {                               // out2  W[256][256]
      int rel = flat - FO2;
      int j = rel & 7, lane = (rel >> 3) & 63, outer = rel >> 9;
      int kc = outer & 7, mt = outer >> 3;
      int m = mt * 16 + (lane & 15);
      int k = kc * 32 + (lane >> 4) * 8 + j;
      val = w_out2[m * 256 + k];
    }
    frags[flat] = f2b(val);
  } else if (flat < FRAG_TOTAL + 256) {    // combined skip bias: sum_l b_skip / 12
    int ch = flat - FRAG_TOTAL;
    float s = 0.f;
    for (int l = 0; l < 12; l++) s += b_skip[l * 256 + ch];
    bsk[ch] = s * (1.0f / 12.0f);
  } else if (flat < PREP_TOTAL) {          // bf16 copy of emb [256][256]
    int i = flat - FRAG_TOTAL - 256;
    embf[i] = f2b(emb[i]);
  }
}

// ------------------------------- main kernel -------------------------------
extern "C" __global__ void __launch_bounds__(512, 2) wavenet_main(
    const int* __restrict__ tokens,
    const unsigned short* __restrict__ embf,
    const unsigned short* __restrict__ frags,
    const float* __restrict__ bsk,
    const float* __restrict__ b_init,
    const float* __restrict__ b_dil,
    const float* __restrict__ b_res,
    const float* __restrict__ b_out1,
    const float* __restrict__ b_out2,
    float* __restrict__ out)
{
  extern __shared__ char lds[];
  unsigned short* xb = (unsigned short*)(lds + X_OFF);  // [160][136] x (bf16)
  unsigned short* gb = (unsigned short*)(lds + G_OFF);  // [160][72]  g (bf16)
  unsigned short* sb = (unsigned short*)(lds + S_OFF);  // [128][264] s/t1

  const int tid = threadIdx.x;
  const int lane = tid & 63;
  const int w = tid >> 6;        // 0..7
  const int l16 = lane & 15;
  const int q = lane >> 4;
  const int wm = w & 3;          // conv M-group: M-tiles {wm, wm+4} (gate pairing)
  const int wn = w >> 2;         // conv N-group (0..1)
  const int bb = blockIdx.x >> 6;
  const int chunk = blockIdx.x & 63;
  const int tb = chunk * TT - HALO;   // abs t of buffer col 0

  int ncol[5];
#pragma unroll
  for (int jn = 0; jn < 5; jn++) ncol[jn] = (wn * 5 + jn) * 16 + l16;

  const short8 zero8 = {0, 0, 0, 0, 0, 0, 0, 0};
  f32x4 acc[2][5];   // conv / res accumulators
  f32x4 sk[2][8];    // persistent skip accumulators (then out1/out2)

  // ---- phase A: init conv (B-frags gathered straight from bf16 emb copy) ----
  int tk[5][2];
#pragma unroll
  for (int jn = 0; jn < 5; jn++) {
#pragma unroll
    for (int s = 0; s < 2; s++) {
      int shift = s ? 0 : 1;     // tap0 <-> x[t-1], tap1 <-> x[t]
      int tsrc = tb + ncol[jn] - shift;
      tk[jn][s] = (tsrc >= 0) ? tokens[bb * T_TOK + tsrc] : -1;
    }
  }
#pragma unroll
  for (int i = 0; i < 2; i++) {
    f32x4 bv;
#pragma unroll
    for (int r = 0; r < 4; r++) bv[r] = b_init[(wm + 4 * i) * 16 + q * 4 + r];
#pragma unroll
    for (int jn = 0; jn < 5; jn++) acc[i][jn] = bv;
  }
#pragma unroll
  for (int s = 0; s < 2; s++) {
#pragma unroll
    for (int kc = 0; kc < 8; kc++) {
      short8 a0 = *(const short8*)(frags + FI + (((s * 8 + wm    ) * 8 + kc) * 64 + lane) * 8);
      short8 a1 = *(const short8*)(frags + FI + (((s * 8 + wm + 4) * 8 + kc) * 64 + lane) * 8);
#pragma unroll
      for (int jn = 0; jn < 5; jn++) {
        int t = tk[jn][s];
        int ts = t < 0 ? 0 : t;
        short8 bv = *(const short8*)(embf + ts * 256 + kc * 32 + q * 8);
        if (t < 0) bv = zero8;
        acc[0][jn] = MFMA(a0, bv, acc[0][jn]);
        acc[1][jn] = MFMA(a1, bv, acc[1][jn]);
      }
    }
  }
#pragma unroll
  for (int i = 0; i < 2; i++) {
#pragma unroll
    for (int jn = 0; jn < 5; jn++) {
      short4v pk;
#pragma unroll
      for (int r = 0; r < 4; r++) pk[r] = (short)f2b(acc[i][jn][r]);
      if (tb + ncol[jn] < 0) { pk[0] = 0; pk[1] = 0; pk[2] = 0; pk[3] = 0; }
      *(short4v*)(xb + ncol[jn] * XSTE + (wm + 4 * i) * 16 + q * 4) = pk;
    }
  }
  // init persistent skip accumulators with combined bias
#pragma unroll
  for (int i = 0; i < 2; i++) {
    f32x4 bv;
#pragma unroll
    for (int r = 0; r < 4; r++) bv[r] = bsk[(2 * w + i) * 16 + q * 4 + r];
#pragma unroll
    for (int jt = 0; jt < 8; jt++) sk[i][jt] = bv;
  }
  __syncthreads();

  // ---- 12 layers ----
  for (int layer = 0; layer < 12; layer++) {
    // dilated conv (dil=2): acc = W*x + b_dil
#pragma unroll
    for (int i = 0; i < 2; i++) {
      f32x4 bv;
#pragma unroll
      for (int r = 0; r < 4; r++) bv[r] = b_dil[layer * 128 + (wm + 4 * i) * 16 + q * 4 + r];
#pragma unroll
      for (int jn = 0; jn < 5; jn++) acc[i][jn] = bv;
    }
#pragma unroll
    for (int s = 0; s < 2; s++) {
      const int shift = s ? 0 : 2;
#pragma unroll
      for (int kc = 0; kc < 4; kc++) {
        short8 a0 = *(const short8*)(frags + FD + ((((layer * 2 + s) * 8 + wm    ) * 4 + kc) * 64 + lane) * 8);
        short8 a1 = *(const short8*)(frags + FD + ((((layer * 2 + s) * 8 + wm + 4) * 4 + kc) * 64 + lane) * 8);
#pragma unroll
        for (int jn = 0; jn < 5; jn++) {
          int c = ncol[jn] - shift; if (c < 0) c = 0;   // clamp: garbage contained
          short8 bv = *(const short8*)(xb + c * XSTE + kc * 32 + q * 8);
          acc[0][jn] = MFMA(a0, bv, acc[0][jn]);
          acc[1][jn] = MFMA(a1, bv, acc[1][jn]);
        }
      }
    }
    // gate: ch [0,64) tanh half (tile wm), ch [64,128) sigmoid half (tile wm+4)
#pragma unroll
    for (int jn = 0; jn < 5; jn++) {
      short4v pk;
#pragma unroll
      for (int r = 0; r < 4; r++) {
        float xt = acc[0][jn][r];
        float xs = acc[1][jn][r];
        float th = 1.f - 2.f / (__expf(2.f * xt) + 1.f);
        float sg = 1.f / (1.f + __expf(-xs));
        pk[r] = (short)f2b(th * sg);
      }
      if (tb + ncol[jn] < 0) { pk[0] = 0; pk[1] = 0; pk[2] = 0; pk[3] = 0; }
      *(short4v*)(gb + ncol[jn] * GSTE + wm * 16 + q * 4) = pk;
    }
    __syncthreads();
    // skip GEMM into persistent accumulators (central 128 cols only)
#pragma unroll
    for (int kc = 0; kc < 2; kc++) {
      short8 a0 = *(const short8*)(frags + FS + (((layer * 16 + 2 * w    ) * 2 + kc) * 64 + lane) * 8);
      short8 a1 = *(const short8*)(frags + FS + (((layer * 16 + 2 * w + 1) * 2 + kc) * 64 + lane) * 8);
#pragma unroll
      for (int jt = 0; jt < 8; jt++) {
        short8 bv = *(const short8*)(gb + (HALO + jt * 16 + l16) * GSTE + kc * 32 + q * 8);
        sk[0][jt] = MFMA(a0, bv, sk[0][jt]);
        sk[1][jt] = MFMA(a1, bv, sk[1][jt]);
      }
    }
    // res GEMM (all 160 cols) then x += res
#pragma unroll
    for (int i = 0; i < 2; i++) {
      f32x4 bv;
#pragma unroll
      for (int r = 0; r < 4; r++) bv[r] = b_res[layer * 128 + (wm + 4 * i) * 16 + q * 4 + r];
#pragma unroll
      for (int jn = 0; jn < 5; jn++) acc[i][jn] = bv;
    }
#pragma unroll
    for (int kc = 0; kc < 2; kc++) {
      short8 a0 = *(const short8*)(frags + FR + (((layer * 8 + wm    ) * 2 + kc) * 64 + lane) * 8);
      short8 a1 = *(const short8*)(frags + FR + (((layer * 8 + wm + 4) * 2 + kc) * 64 + lane) * 8);
#pragma unroll
      for (int jn = 0; jn < 5; jn++) {
        short8 bv = *(const short8*)(gb + ncol[jn] * GSTE + kc * 32 + q * 8);
        acc[0][jn] = MFMA(a0, bv, acc[0][jn]);
        acc[1][jn] = MFMA(a1, bv, acc[1][jn]);
      }
    }
#pragma unroll
    for (int i = 0; i < 2; i++) {
#pragma unroll
      for (int jn = 0; jn < 5; jn++) {
        unsigned short* p = xb + ncol[jn] * XSTE + (wm + 4 * i) * 16 + q * 4;
        short4v old = *(short4v*)p;
        short4v pk;
#pragma unroll
        for (int r = 0; r < 4; r++) {
          float xo = __builtin_bit_cast(float, (unsigned int)(unsigned short)old[r] << 16);
          pk[r] = (short)f2b(acc[i][jn][r] + xo);
        }
        if (tb + ncol[jn] < 0) { pk[0] = 0; pk[1] = 0; pk[2] = 0; pk[3] = 0; }
        *(short4v*)p = pk;
      }
    }
    __syncthreads();
  }

  // ---- epilogue: s = relu(skip_mean) -> out1 -> relu -> out2 ----
#pragma unroll
  for (int i = 0; i < 2; i++) {
#pragma unroll
    for (int jt = 0; jt < 8; jt++) {
      short4v pk;
#pragma unroll
      for (int r = 0; r < 4; r++) pk[r] = (short)f2b(fmaxf(sk[i][jt][r], 0.f));
      *(short4v*)(sb + (jt * 16 + l16) * SSTE + (2 * w + i) * 16 + q * 4) = pk;
    }
  }
  __syncthreads();
  // out1
#pragma unroll
  for (int i = 0; i < 2; i++) {
    f32x4 bv;
#pragma unroll
    for (int r = 0; r < 4; r++) bv[r] = b_out1[(2 * w + i) * 16 + q * 4 + r];
#pragma unroll
    for (int jt = 0; jt < 8; jt++) sk[i][jt] = bv;
  }
#pragma unroll
  for (int kc = 0; kc < 8; kc++) {
    short8 a0 = *(const short8*)(frags + FO1 + (((2 * w    ) * 8 + kc) * 64 + lane) * 8);
    short8 a1 = *(const short8*)(frags + FO1 + (((2 * w + 1) * 8 + kc) * 64 + lane) * 8);
#pragma unroll
    for (int jt = 0; jt < 8; jt++) {
      short8 bv = *(const short8*)(sb + (jt * 16 + l16) * SSTE + kc * 32 + q * 8);
      sk[0][jt] = MFMA(a0, bv, sk[0][jt]);
      sk[1][jt] = MFMA(a1, bv, sk[1][jt]);
    }
  }
  short4v t1p[2][8];
#pragma unroll
  for (int i = 0; i < 2; i++) {
#pragma unroll
    for (int jt = 0; jt < 8; jt++) {
#pragma unroll
      for (int r = 0; r < 4; r++) t1p[i][jt][r] = (short)f2b(fmaxf(sk[i][jt][r], 0.f));
    }
  }
  __syncthreads();   // all reads of s done before overwrite
#pragma unroll
  for (int i = 0; i < 2; i++) {
#pragma unroll
    for (int jt = 0; jt < 8; jt++)
      *(short4v*)(sb + (jt * 16 + l16) * SSTE + (2 * w + i) * 16 + q * 4) = t1p[i][jt];
  }
  __syncthreads();
  // out2
#pragma unroll
  for (int i = 0; i < 2; i++) {
    f32x4 bv;
#pragma unroll
    for (int r = 0; r < 4; r++) bv[r] = b_out2[(2 * w + i) * 16 + q * 4 + r];
#pragma unroll
    for (int jt = 0; jt < 8; jt++) sk[i][jt] = bv;
  }
#pragma unroll
  for (int kc = 0; kc < 8; kc++) {
    short8 a0 = *(const short8*)(frags + FO2 + (((2 * w    ) * 8 + kc) * 64 + lane) * 8);
    short8 a1 = *(const short8*)(frags + FO2 + (((2 * w + 1) * 8 + kc) * 64 + lane) * 8);
#pragma unroll
    for (int jt = 0; jt < 8; jt++) {
      short8 bv = *(const short8*)(sb + (jt * 16 + l16) * SSTE + kc * 32 + q * 8);
      sk[0][jt] = MFMA(a0, bv, sk[0][jt]);
      sk[1][jt] = MFMA(a1, bv, sk[1][jt]);
    }
  }
  // write out [B, V=256, T] as FLOAT32
  const int t0 = chunk * TT;
#pragma unroll
  for (int i = 0; i < 2; i++) {
#pragma unroll
    for (int jt = 0; jt < 8; jt++) {
#pragma unroll
      for (int r = 0; r < 4; r++) {
        int v = (2 * w + i) * 16 + q * 4 + r;
        int t = t0 + jt * 16 + l16;
        out[((size_t)(bb * 256 + v) << 13) + t] = sk[i][jt][r];
      }
    }
  }
}

// ------------------------------- launcher ----------------------------------
extern "C" void kernel_launch(void* const* d_in, const int* in_sizes, int n_in,
                              void* d_out, int out_size, void* d_ws, size_t ws_size,
                              hipStream_t stream) {
  (void)in_sizes; (void)n_in; (void)out_size; (void)ws_size;
  const int*   tokens = (const int*)d_in[0];
  const float* emb    = (const float*)d_in[1];
  const float* w_init = (const float*)d_in[2];
  const float* b_init = (const float*)d_in[3];
  const float* w_dil  = (const float*)d_in[4];
  const float* b_dil  = (const float*)d_in[5];
  const float* w_res  = (const float*)d_in[6];
  const float* b_res  = (const float*)d_in[7];
  const float* w_skip = (const float*)d_in[8];
  const float* b_skip = (const float*)d_in[9];
  const float* w_out1 = (const float*)d_in[10];
  const float* b_out1 = (const float*)d_in[11];
  const float* w_out2 = (const float*)d_in[12];
  const float* b_out2 = (const float*)d_in[13];

  unsigned short* frags = (unsigned short*)d_ws;
  float* bsk = (float*)((char*)d_ws + BSK_BYTE_OFF);
  unsigned short* embf = (unsigned short*)((char*)d_ws + EMBF_BYTE_OFF);

  prep_kernel<<<dim3(PREP_TOTAL / 256), dim3(256), 0, stream>>>(
      emb, w_init, w_dil, w_skip, w_res, w_out1, w_out2, b_skip,
      frags, bsk, embf);

  // opt-in to >64KB dynamic LDS (no-op/harmless where already allowed)
  (void)hipFuncSetAttribute((const void*)wavenet_main,
                            hipFuncAttributeMaxDynamicSharedMemorySize, LDS_BYTES);

  wavenet_main<<<dim3(1024), dim3(512), LDS_BYTES, stream>>>(
      tokens, embf, frags, bsk, b_init, b_dil, b_res, b_out1, b_out2,
      (float*)d_out);
}

// Round 6
// 679.282 us; speedup vs baseline: 1.0191x; 1.0191x over previous
//
#include <hip/hip_runtime.h>

// ---------------------------------------------------------------------------
// Fully-fused WaveNet forward (MFMA). R5 passed at 600us with Occupancy=23%
// (1 block/CU: 134KB LDS). R6 change: overlay the epilogue buffer sb onto
// xb/gb (dead after the final layer barrier) -> LDS 134144 -> 67584 bytes ->
// 2 blocks/CU, 16 waves/CU. Everything else identical to the passing R5.
// ---------------------------------------------------------------------------

typedef __attribute__((ext_vector_type(8))) short short8;   // 8 bf16 (A/B frag)
typedef __attribute__((ext_vector_type(4))) short short4v;  // 4 bf16 pack
typedef __attribute__((ext_vector_type(4))) float f32x4;    // accumulator

#define T_TOK 8192
#define TT    128     // central cols per block
#define HALO  32
#define XSTE  136     // x LDS col stride (128 ch + 8 pad), 272B = 17*16B (odd chunk)
#define GSTE  72      // g LDS col stride (64 ch + 8 pad), 144B = 9*16B (odd chunk)
#define SSTE  264     // s/t1 LDS col stride (256 ch + 8 pad), 528B = 33*16B (odd chunk)
#define X_OFF 0
#define G_OFF 43520                  // 160*136*2
#define S_OFF 0                      // sb OVERLAYS xb/gb (epilogue only)
#define LDS_BYTES 67584              // max(43520+23040, 128*264*2=67584)

// fragment-section bases in d_ws (bf16 elems)
#define FI  0          // init conv: 2 taps * 8 mt * 8 kc * 512
#define FD  65536      // dil conv: 12 * 2 * 8 * 4 * 512
#define FS  458752     // skip:     12 * 16 * 2 * 512   (scaled by 1/12)
#define FR  655360     // res:      12 * 8 * 2 * 512
#define FO1 753664     // out1:     16 * 8 * 512
#define FO2 819200     // out2:     16 * 8 * 512
#define FRAG_TOTAL 884736
#define BSK_BYTE_OFF  (FRAG_TOTAL * 2)          // 256 floats
#define EMBF_BYTE_OFF (BSK_BYTE_OFF + 1024)     // 65536 bf16
#define PREP_TOTAL (FRAG_TOTAL + 256 + 65536)   // = 950528 = 3713*256

#define MFMA(a, b, c) __builtin_amdgcn_mfma_f32_16x16x32_bf16(a, b, c, 0, 0, 0)

__device__ __forceinline__ unsigned short f2b(float f) {
  unsigned int x = __builtin_bit_cast(unsigned int, f);
  return (unsigned short)((x + 0x7fffu + ((x >> 16) & 1u)) >> 16);  // RNE
}

// ---------------- prep: swizzle weights into A-fragment order ----------------
// frag element (outer, lane, j): value = W[mt*16 + (lane&15)][kc*32 + (lane>>4)*8 + j]
__global__ void __launch_bounds__(256) prep_kernel(
    const float* __restrict__ emb,
    const float* __restrict__ w_init,
    const float* __restrict__ w_dil,
    const float* __restrict__ w_skip,
    const float* __restrict__ w_res,
    const float* __restrict__ w_out1,
    const float* __restrict__ w_out2,
    const float* __restrict__ b_skip,
    unsigned short* __restrict__ frags,
    float* __restrict__ bsk,
    unsigned short* __restrict__ embf)
{
  int flat = blockIdx.x * 256 + threadIdx.x;
  if (flat < FRAG_TOTAL) {
    float val;
    if (flat < FD) {                       // init conv  W[128][256][2]
      int rel = flat;
      int j = rel & 7, lane = (rel >> 3) & 63, outer = rel >> 9;
      int kc = outer & 7, mt = (outer >> 3) & 7, tap = outer >> 6;
      int m = mt * 16 + (lane & 15);
      int k = kc * 32 + (lane >> 4) * 8 + j;
      val = w_init[(m * 256 + k) * 2 + tap];
    } else if (flat < FS) {                // dil conv  W[12][128][128][2]
      int rel = flat - FD;
      int j = rel & 7, lane = (rel >> 3) & 63, outer = rel >> 9;
      int kc = outer & 3, mt = (outer >> 2) & 7, tap = (outer >> 5) & 1, l = outer >> 6;
      int m = mt * 16 + (lane & 15);
      int k = kc * 32 + (lane >> 4) * 8 + j;
      val = w_dil[((l * 128 + m) * 128 + k) * 2 + tap];
    } else if (flat < FR) {                // skip  W[12][256][64], scaled 1/12
      int rel = flat - FS;
      int j = rel & 7, lane = (rel >> 3) & 63, outer = rel >> 9;
      int kc = outer & 1, mt = (outer >> 1) & 15, l = outer >> 5;
      int m = mt * 16 + (lane & 15);
      int k = kc * 32 + (lane >> 4) * 8 + j;
      val = w_skip[(l * 256 + m) * 64 + k] * (1.0f / 12.0f);
    } else if (flat < FO1) {               // res  W[12][128][64]
      int rel = flat - FR;
      int j = rel & 7, lane = (rel >> 3) & 63, outer = rel >> 9;
      int kc = outer & 1, mt = (outer >> 1) & 7, l = outer >> 4;
      int m = mt * 16 + (lane & 15);
      int k = kc * 32 + (lane >> 4) * 8 + j;
      val = w_res[(l * 128 + m) * 64 + k];
    } else if (flat < FO2) {               // out1  W[256][256]
      int rel = flat - FO1;
      int j = rel & 7, lane = (rel >> 3) & 63, outer = rel >> 9;
      int kc = outer & 7, mt = outer >> 3;
      int m = mt * 16 + (lane & 15);
      int k = kc * 32 + (lane >> 4) * 8 + j;
      val = w_out1[m * 256 + k];
    } else {                               // out2  W[256][256]
      int rel = flat - FO2;
      int j = rel & 7, lane = (rel >> 3) & 63, outer = rel >> 9;
      int kc = outer & 7, mt = outer >> 3;
      int m = mt * 16 + (lane & 15);
      int k = kc * 32 + (lane >> 4) * 8 + j;
      val = w_out2[m * 256 + k];
    }
    frags[flat] = f2b(val);
  } else if (flat < FRAG_TOTAL + 256) {    // combined skip bias: sum_l b_skip / 12
    int ch = flat - FRAG_TOTAL;
    float s = 0.f;
    for (int l = 0; l < 12; l++) s += b_skip[l * 256 + ch];
    bsk[ch] = s * (1.0f / 12.0f);
  } else if (flat < PREP_TOTAL) {          // bf16 copy of emb [256][256]
    int i = flat - FRAG_TOTAL - 256;
    embf[i] = f2b(emb[i]);
  }
}

// ------------------------------- main kernel -------------------------------
extern "C" __global__ void __launch_bounds__(512, 4) wavenet_main(
    const int* __restrict__ tokens,
    const unsigned short* __restrict__ embf,
    const unsigned short* __restrict__ frags,
    const float* __restrict__ bsk,
    const float* __restrict__ b_init,
    const float* __restrict__ b_dil,
    const float* __restrict__ b_res,
    const float* __restrict__ b_out1,
    const float* __restrict__ b_out2,
    float* __restrict__ out)
{
  extern __shared__ char lds[];
  unsigned short* xb = (unsigned short*)(lds + X_OFF);  // [160][136] x (bf16)
  unsigned short* gb = (unsigned short*)(lds + G_OFF);  // [160][72]  g (bf16)
  unsigned short* sb = (unsigned short*)(lds + S_OFF);  // [128][264] s/t1 (overlay)

  const int tid = threadIdx.x;
  const int lane = tid & 63;
  const int w = tid >> 6;        // 0..7
  const int l16 = lane & 15;
  const int q = lane >> 4;
  const int wm = w & 3;          // conv M-group: M-tiles {wm, wm+4} (gate pairing)
  const int wn = w >> 2;         // conv N-group (0..1)
  const int bb = blockIdx.x >> 6;
  const int chunk = blockIdx.x & 63;
  const int tb = chunk * TT - HALO;   // abs t of buffer col 0

  int ncol[5];
#pragma unroll
  for (int jn = 0; jn < 5; jn++) ncol[jn] = (wn * 5 + jn) * 16 + l16;

  const short8 zero8 = {0, 0, 0, 0, 0, 0, 0, 0};
  f32x4 acc[2][5];   // conv / res accumulators
  f32x4 sk[2][8];    // persistent skip accumulators (then out1/out2)

  // ---- phase A: init conv (B-frags gathered straight from bf16 emb copy) ----
  int tk[5][2];
#pragma unroll
  for (int jn = 0; jn < 5; jn++) {
#pragma unroll
    for (int s = 0; s < 2; s++) {
      int shift = s ? 0 : 1;     // tap0 <-> x[t-1], tap1 <-> x[t]
      int tsrc = tb + ncol[jn] - shift;
      tk[jn][s] = (tsrc >= 0) ? tokens[bb * T_TOK + tsrc] : -1;
    }
  }
#pragma unroll
  for (int i = 0; i < 2; i++) {
    f32x4 bv;
#pragma unroll
    for (int r = 0; r < 4; r++) bv[r] = b_init[(wm + 4 * i) * 16 + q * 4 + r];
#pragma unroll
    for (int jn = 0; jn < 5; jn++) acc[i][jn] = bv;
  }
#pragma unroll
  for (int s = 0; s < 2; s++) {
#pragma unroll
    for (int kc = 0; kc < 8; kc++) {
      short8 a0 = *(const short8*)(frags + FI + (((s * 8 + wm    ) * 8 + kc) * 64 + lane) * 8);
      short8 a1 = *(const short8*)(frags + FI + (((s * 8 + wm + 4) * 8 + kc) * 64 + lane) * 8);
#pragma unroll
      for (int jn = 0; jn < 5; jn++) {
        int t = tk[jn][s];
        int ts = t < 0 ? 0 : t;
        short8 bv = *(const short8*)(embf + ts * 256 + kc * 32 + q * 8);
        if (t < 0) bv = zero8;
        acc[0][jn] = MFMA(a0, bv, acc[0][jn]);
        acc[1][jn] = MFMA(a1, bv, acc[1][jn]);
      }
    }
  }
#pragma unroll
  for (int i = 0; i < 2; i++) {
#pragma unroll
    for (int jn = 0; jn < 5; jn++) {
      short4v pk;
#pragma unroll
      for (int r = 0; r < 4; r++) pk[r] = (short)f2b(acc[i][jn][r]);
      if (tb + ncol[jn] < 0) { pk[0] = 0; pk[1] = 0; pk[2] = 0; pk[3] = 0; }
      *(short4v*)(xb + ncol[jn] * XSTE + (wm + 4 * i) * 16 + q * 4) = pk;
    }
  }
  // init persistent skip accumulators with combined bias
#pragma unroll
  for (int i = 0; i < 2; i++) {
    f32x4 bv;
#pragma unroll
    for (int r = 0; r < 4; r++) bv[r] = bsk[(2 * w + i) * 16 + q * 4 + r];
#pragma unroll
    for (int jt = 0; jt < 8; jt++) sk[i][jt] = bv;
  }
  __syncthreads();

  // ---- 12 layers ----
  for (int layer = 0; layer < 12; layer++) {
    // dilated conv (dil=2): acc = W*x + b_dil
#pragma unroll
    for (int i = 0; i < 2; i++) {
      f32x4 bv;
#pragma unroll
      for (int r = 0; r < 4; r++) bv[r] = b_dil[layer * 128 + (wm + 4 * i) * 16 + q * 4 + r];
#pragma unroll
      for (int jn = 0; jn < 5; jn++) acc[i][jn] = bv;
    }
#pragma unroll
    for (int s = 0; s < 2; s++) {
      const int shift = s ? 0 : 2;
#pragma unroll
      for (int kc = 0; kc < 4; kc++) {
        short8 a0 = *(const short8*)(frags + FD + ((((layer * 2 + s) * 8 + wm    ) * 4 + kc) * 64 + lane) * 8);
        short8 a1 = *(const short8*)(frags + FD + ((((layer * 2 + s) * 8 + wm + 4) * 4 + kc) * 64 + lane) * 8);
#pragma unroll
        for (int jn = 0; jn < 5; jn++) {
          int c = ncol[jn] - shift; if (c < 0) c = 0;   // clamp: garbage contained
          short8 bv = *(const short8*)(xb + c * XSTE + kc * 32 + q * 8);
          acc[0][jn] = MFMA(a0, bv, acc[0][jn]);
          acc[1][jn] = MFMA(a1, bv, acc[1][jn]);
        }
      }
    }
    // gate: ch [0,64) tanh half (tile wm), ch [64,128) sigmoid half (tile wm+4)
#pragma unroll
    for (int jn = 0; jn < 5; jn++) {
      short4v pk;
#pragma unroll
      for (int r = 0; r < 4; r++) {
        float xt = acc[0][jn][r];
        float xs = acc[1][jn][r];
        float th = 1.f - 2.f / (__expf(2.f * xt) + 1.f);
        float sg = 1.f / (1.f + __expf(-xs));
        pk[r] = (short)f2b(th * sg);
      }
      if (tb + ncol[jn] < 0) { pk[0] = 0; pk[1] = 0; pk[2] = 0; pk[3] = 0; }
      *(short4v*)(gb + ncol[jn] * GSTE + wm * 16 + q * 4) = pk;
    }
    __syncthreads();
    // skip GEMM into persistent accumulators (central 128 cols only)
#pragma unroll
    for (int kc = 0; kc < 2; kc++) {
      short8 a0 = *(const short8*)(frags + FS + (((layer * 16 + 2 * w    ) * 2 + kc) * 64 + lane) * 8);
      short8 a1 = *(const short8*)(frags + FS + (((layer * 16 + 2 * w + 1) * 2 + kc) * 64 + lane) * 8);
#pragma unroll
      for (int jt = 0; jt < 8; jt++) {
        short8 bv = *(const short8*)(gb + (HALO + jt * 16 + l16) * GSTE + kc * 32 + q * 8);
        sk[0][jt] = MFMA(a0, bv, sk[0][jt]);
        sk[1][jt] = MFMA(a1, bv, sk[1][jt]);
      }
    }
    // res GEMM (all 160 cols) then x += res
#pragma unroll
    for (int i = 0; i < 2; i++) {
      f32x4 bv;
#pragma unroll
      for (int r = 0; r < 4; r++) bv[r] = b_res[layer * 128 + (wm + 4 * i) * 16 + q * 4 + r];
#pragma unroll
      for (int jn = 0; jn < 5; jn++) acc[i][jn] = bv;
    }
#pragma unroll
    for (int kc = 0; kc < 2; kc++) {
      short8 a0 = *(const short8*)(frags + FR + (((layer * 8 + wm    ) * 2 + kc) * 64 + lane) * 8);
      short8 a1 = *(const short8*)(frags + FR + (((layer * 8 + wm + 4) * 2 + kc) * 64 + lane) * 8);
#pragma unroll
      for (int jn = 0; jn < 5; jn++) {
        short8 bv = *(const short8*)(gb + ncol[jn] * GSTE + kc * 32 + q * 8);
        acc[0][jn] = MFMA(a0, bv, acc[0][jn]);
        acc[1][jn] = MFMA(a1, bv, acc[1][jn]);
      }
    }
#pragma unroll
    for (int i = 0; i < 2; i++) {
#pragma unroll
      for (int jn = 0; jn < 5; jn++) {
        unsigned short* p = xb + ncol[jn] * XSTE + (wm + 4 * i) * 16 + q * 4;
        short4v old = *(short4v*)p;
        short4v pk;
#pragma unroll
        for (int r = 0; r < 4; r++) {
          float xo = __builtin_bit_cast(float, (unsigned int)(unsigned short)old[r] << 16);
          pk[r] = (short)f2b(acc[i][jn][r] + xo);
        }
        if (tb + ncol[jn] < 0) { pk[0] = 0; pk[1] = 0; pk[2] = 0; pk[3] = 0; }
        *(short4v*)p = pk;
      }
    }
    __syncthreads();
  }

  // ---- epilogue: s = relu(skip_mean) -> out1 -> relu -> out2 ----
  // sb overlays xb/gb; all xb/gb reads completed before the final layer barrier.
#pragma unroll
  for (int i = 0; i < 2; i++) {
#pragma unroll
    for (int jt = 0; jt < 8; jt++) {
      short4v pk;
#pragma unroll
      for (int r = 0; r < 4; r++) pk[r] = (short)f2b(fmaxf(sk[i][jt][r], 0.f));
      *(short4v*)(sb + (jt * 16 + l16) * SSTE + (2 * w + i) * 16 + q * 4) = pk;
    }
  }
  __syncthreads();
  // out1
#pragma unroll
  for (int i = 0; i < 2; i++) {
    f32x4 bv;
#pragma unroll
    for (int r = 0; r < 4; r++) bv[r] = b_out1[(2 * w + i) * 16 + q * 4 + r];
#pragma unroll
    for (int jt = 0; jt < 8; jt++) sk[i][jt] = bv;
  }
#pragma unroll
  for (int kc = 0; kc < 8; kc++) {
    short8 a0 = *(const short8*)(frags + FO1 + (((2 * w    ) * 8 + kc) * 64 + lane) * 8);
    short8 a1 = *(const short8*)(frags + FO1 + (((2 * w + 1) * 8 + kc) * 64 + lane) * 8);
#pragma unroll
    for (int jt = 0; jt < 8; jt++) {
      short8 bv = *(const short8*)(sb + (jt * 16 + l16) * SSTE + kc * 32 + q * 8);
      sk[0][jt] = MFMA(a0, bv, sk[0][jt]);
      sk[1][jt] = MFMA(a1, bv, sk[1][jt]);
    }
  }
  short4v t1p[2][8];
#pragma unroll
  for (int i = 0; i < 2; i++) {
#pragma unroll
    for (int jt = 0; jt < 8; jt++) {
#pragma unroll
      for (int r = 0; r < 4; r++) t1p[i][jt][r] = (short)f2b(fmaxf(sk[i][jt][r], 0.f));
    }
  }
  __syncthreads();   // all reads of s done before overwrite
#pragma unroll
  for (int i = 0; i < 2; i++) {
#pragma unroll
    for (int jt = 0; jt < 8; jt++)
      *(short4v*)(sb + (jt * 16 + l16) * SSTE + (2 * w + i) * 16 + q * 4) = t1p[i][jt];
  }
  __syncthreads();
  // out2
#pragma unroll
  for (int i = 0; i < 2; i++) {
    f32x4 bv;
#pragma unroll
    for (int r = 0; r < 4; r++) bv[r] = b_out2[(2 * w + i) * 16 + q * 4 + r];
#pragma unroll
    for (int jt = 0; jt < 8; jt++) sk[i][jt] = bv;
  }
#pragma unroll
  for (int kc = 0; kc < 8; kc++) {
    short8 a0 = *(const short8*)(frags + FO2 + (((2 * w    ) * 8 + kc) * 64 + lane) * 8);
    short8 a1 = *(const short8*)(frags + FO2 + (((2 * w + 1) * 8 + kc) * 64 + lane) * 8);
#pragma unroll
    for (int jt = 0; jt < 8; jt++) {
      short8 bv = *(const short8*)(sb + (jt * 16 + l16) * SSTE + kc * 32 + q * 8);
      sk[0][jt] = MFMA(a0, bv, sk[0][jt]);
      sk[1][jt] = MFMA(a1, bv, sk[1][jt]);
    }
  }
  // write out [B, V=256, T] as FLOAT32
  const int t0 = chunk * TT;
#pragma unroll
  for (int i = 0; i < 2; i++) {
#pragma unroll
    for (int jt = 0; jt < 8; jt++) {
#pragma unroll
      for (int r = 0; r < 4; r++) {
        int v = (2 * w + i) * 16 + q * 4 + r;
        int t = t0 + jt * 16 + l16;
        out[((size_t)(bb * 256 + v) << 13) + t] = sk[i][jt][r];
      }
    }
  }
}

// ------------------------------- launcher ----------------------------------
extern "C" void kernel_launch(void* const* d_in, const int* in_sizes, int n_in,
                              void* d_out, int out_size, void* d_ws, size_t ws_size,
                              hipStream_t stream) {
  (void)in_sizes; (void)n_in; (void)out_size; (void)ws_size;
  const int*   tokens = (const int*)d_in[0];
  const float* emb    = (const float*)d_in[1];
  const float* w_init = (const float*)d_in[2];
  const float* b_init = (const float*)d_in[3];
  const float* w_dil  = (const float*)d_in[4];
  const float* b_dil  = (const float*)d_in[5];
  const float* w_res  = (const float*)d_in[6];
  const float* b_res  = (const float*)d_in[7];
  const float* w_skip = (const float*)d_in[8];
  const float* b_skip = (const float*)d_in[9];
  const float* w_out1 = (const float*)d_in[10];
  const float* b_out1 = (const float*)d_in[11];
  const float* w_out2 = (const float*)d_in[12];
  const float* b_out2 = (const float*)d_in[13];

  unsigned short* frags = (unsigned short*)d_ws;
  float* bsk = (float*)((char*)d_ws + BSK_BYTE_OFF);
  unsigned short* embf = (unsigned short*)((char*)d_ws + EMBF_BYTE_OFF);

  prep_kernel<<<dim3(PREP_TOTAL / 256), dim3(256), 0, stream>>>(
      emb, w_init, w_dil, w_skip, w_res, w_out1, w_out2, b_skip,
      frags, bsk, embf);

  // opt-in to >64KB dynamic LDS (no-op/harmless where already allowed)
  (void)hipFuncSetAttribute((const void*)wavenet_main,
                            hipFuncAttributeMaxDynamicSharedMemorySize, LDS_BYTES);

  wavenet_main<<<dim3(1024), dim3(512), LDS_BYTES, stream>>>(
      tokens, embf, frags, bsk, b_init, b_dil, b_res, b_out1, b_out2,
      (float*)d_out);
}